// Round 8
// baseline (257.215 us; speedup 1.0000x reference)
//
#include <hip/hip_runtime.h>

static constexpr int Lc = 512;
static constexpr int Bc = 256;
static constexpr int Tc = 128;

// DPP quad-permute add (R3-proven): lanes 2m <-> 2m+1 exchange, VALU-speed.
template <int CTRL>
__device__ __forceinline__ float quad_add(float x) {
  const int y = __builtin_amdgcn_update_dpp(0, __float_as_int(x), CTRL, 0xf, 0xf, true);
  return x + __int_as_float(y);
}

// 4 waves per batch element: 256 blocks x 256 threads.
// Lane pair (2m,2m+1) of wave w owns column j = w*32+m; ih = lane&1 selects
// i-half [ih*64, ih*64+64). E-half in 64 f32 VGPRs. p is f32[128] in LDS.
// Per-step sync: ds_write -> s_waitcnt lgkmcnt(0) -> raw s_barrier.
// vmcnt is NEVER drained in the loop (em prefetch stays in flight across
// barriers) — this is the fix for R3's ~900cyc/step barrier cost.
__launch_bounds__(256, 1)
__global__ void crf_llh_kernel(const float* __restrict__ emis,
                               const int* __restrict__ tags,
                               const int* __restrict__ mask,
                               const float* __restrict__ startT,
                               const float* __restrict__ endT,
                               const float* __restrict__ trans,
                               float* __restrict__ partial)
{
  const int b   = blockIdx.x;
  const int tid = threadIdx.x;
  const int w   = tid >> 6;       // wave 0..3
  const int l   = tid & 63;       // lane
  const int j   = w * 32 + (l >> 1);   // output column 0..127
  const int ih  = l & 1;               // i-half

  __shared__ __align__(16) float p_lds[2][128];
  __shared__ int expo_lds[2];
  __shared__ float wredA[4];
  __shared__ float wredB[4];

  // ---------------- numerator (gold-path score) ----------------
  float v = 0.f, c = 0.f;
  for (int t = tid; t < Lc; t += 256) {
    const float mf  = (float)mask[t * Bc + b];
    const int tag_t = tags[t * Bc + b];
    float e = emis[((size_t)t * Bc + b) * Tc + tag_t] * mf;
    if (t >= 1) e += trans[tags[(t - 1) * Bc + b] * Tc + tag_t] * mf;
    v += e; c += mf;
  }
  #pragma unroll
  for (int o = 1; o < 64; o <<= 1) {
    v += __shfl_xor(v, o);
    c += __shfl_xor(c, o);
  }
  if (l == 0) { wredA[w] = v; wredB[w] = c; }
  __syncthreads();
  float score = 0.f;   // valid on tid 0
  if (tid == 0) {
    const float sv = (wredA[0] + wredA[1]) + (wredA[2] + wredA[3]);
    const float sc = (wredB[0] + wredB[1]) + (wredB[2] + wredB[3]);
    const int last_idx = (int)(sc + 0.5f) - 1;
    score = sv + startT[tags[b]] + endT[tags[last_idx * Bc + b]];
  }
  __syncthreads();   // wredA/wredB reused below

  // ---------------- E half-column: 64 f32 VGPRs ----------------
  float Ef[64];
  #pragma unroll
  for (int k = 0; k < 64; ++k)
    Ef[k] = __expf(trans[(ih * 64 + k) * Tc + j]);
  const float eEnd = __expf(endT[j]);

  // ---------------- init t = 0 ----------------
  const size_t strideT = (size_t)Bc * Tc;
  const float lp0 = startT[j] + emis[(size_t)b * Tc + j];
  float wm = lp0;
  #pragma unroll
  for (int o = 1; o < 64; o <<= 1) wm = fmaxf(wm, __shfl_xor(wm, o));
  if (l == 0) wredA[w] = wm;
  __syncthreads();
  const float M0 = fmaxf(fmaxf(wredA[0], wredA[1]), fmaxf(wredA[2], wredA[3]));

  float pPrev = __expf(lp0 - M0);
  if (ih == 0)  p_lds[0][j] = pPrev;
  if (tid == 0) expo_lds[0] = 0;

  // em/mask prefetch pipeline, 3 deep (loads stay in flight across barriers)
  const float* emp = emis + (size_t)b * Tc + j;
  float emR0 = emp[1 * strideT];           // em[t=1]
  float emR1 = emp[2 * strideT];
  float emR2 = emp[3 * strideT];
  int   mR0  = mask[1 * Bc + b];
  int   mR1  = mask[2 * Bc + b];
  int   mR2  = mask[3 * Bc + b];
  const float* emp3 = emp + 4 * strideT;   // next load address (t=4)
  const int*   mp3  = mask + 4 * Bc + b;

  __syncthreads();   // p_lds[0] + expo_lds[0] + wredA(M0) ready

  // ---------------- forward recurrence ----------------
  int Ksum = 0;
  int buf  = 0;
  for (int t = 1; t < Lc; ++t) {
    // uniform rescale exponent for this step (from col0, previous step)
    const int e0 = expo_lds[buf];

    // read own i-half of p: 16x float4, 2 broadcast addresses per read
    const float4* pv = (const float4*)&p_lds[buf][ih * 64];

    const float eEm = __expf(emR0);

    // prefetch t+3 (kept in flight across the barrier — no vmcnt drain)
    float emNew = 0.f; int mNew = 0;
    if (t + 3 < Lc) {
      emNew = emp3[0];
      mNew  = mp3[0];
      emp3 += strideT;
      mp3  += Bc;
    }

    // s_half = sum over this lane's 64 i's
    float a0 = 0.f, a1 = 0.f, a2 = 0.f, a3 = 0.f;
    float a4 = 0.f, a5 = 0.f, a6 = 0.f, a7 = 0.f;
    #pragma unroll
    for (int q = 0; q < 16; ++q) {
      const float4 pp = pv[q];
      if (q & 1) {
        a4 = fmaf(pp.x, Ef[4 * q + 0], a4);
        a5 = fmaf(pp.y, Ef[4 * q + 1], a5);
        a6 = fmaf(pp.z, Ef[4 * q + 2], a6);
        a7 = fmaf(pp.w, Ef[4 * q + 3], a7);
      } else {
        a0 = fmaf(pp.x, Ef[4 * q + 0], a0);
        a1 = fmaf(pp.y, Ef[4 * q + 1], a1);
        a2 = fmaf(pp.z, Ef[4 * q + 2], a2);
        a3 = fmaf(pp.w, Ef[4 * q + 3], a3);
      }
    }
    float s = ((a0 + a1) + (a2 + a3)) + ((a4 + a5) + (a6 + a7));
    s = quad_add<0xB1>(s);   // combine i-halves (lanes 2m <-> 2m+1)

    const float r  = __uint_as_float((unsigned)(127 - e0) << 23);  // 2^-e0
    float pn = (mR0 ? s * eEm : pPrev) * r;
    Ksum += e0;
    pPrev = pn;

    const int nxt = buf ^ 1;
    if (ih == 0) p_lds[nxt][j] = pn;
    if (tid == 0) {
      int e = (int)((__float_as_uint(pn) >> 23) & 0xff) - 127;
      expo_lds[nxt] = min(max(e, -100), 100);
    }

    // advance prefetch pipeline
    emR0 = emR1; emR1 = emR2; emR2 = emNew;
    mR0  = mR1;  mR1  = mR2;  mR2  = mNew;

    // raw barrier: drain LDS only; global loads stay in flight
    asm volatile("s_waitcnt lgkmcnt(0)" ::: "memory");
    __builtin_amdgcn_s_barrier();
    asm volatile("" ::: "memory");   // keep next step's LDS reads below barrier

    buf = nxt;
  }

  // ---------------- final LSE ----------------
  float contrib = (ih == 0) ? pPrev * eEnd : 0.f;
  #pragma unroll
  for (int o = 1; o < 64; o <<= 1) contrib += __shfl_xor(contrib, o);
  if (l == 0) wredA[w] = contrib;
  __syncthreads();
  if (tid == 0) {
    const float ssum = (wredA[0] + wredA[1]) + (wredA[2] + wredA[3]);
    const float denom = M0 + (float)Ksum * 0.69314718055994531f + __logf(ssum);
    partial[b] = score - denom;
  }
}

// Deterministic final reduction of 256 per-batch llh values -> scalar.
__global__ void crf_reduce(const float* __restrict__ partial, float* __restrict__ out)
{
  const int tid = threadIdx.x;  // 256 threads
  float v = partial[tid];
  #pragma unroll
  for (int o = 1; o < 64; o <<= 1) v += __shfl_xor(v, o);
  __shared__ float ws[4];
  if ((tid & 63) == 0) ws[tid >> 6] = v;
  __syncthreads();
  if (tid == 0) out[0] = (ws[0] + ws[1]) + (ws[2] + ws[3]);
}

extern "C" void kernel_launch(void* const* d_in, const int* in_sizes, int n_in,
                              void* d_out, int out_size, void* d_ws, size_t ws_size,
                              hipStream_t stream)
{
  const float* emis   = (const float*)d_in[0];
  const int*   tags   = (const int*)d_in[1];
  const int*   mask   = (const int*)d_in[2];
  const float* startT = (const float*)d_in[3];
  const float* endT   = (const float*)d_in[4];
  const float* trans  = (const float*)d_in[5];

  float* partial = (float*)d_ws;  // 256 floats

  crf_llh_kernel<<<Bc, 256, 0, stream>>>(emis, tags, mask, startT, endT, trans, partial);
  crf_reduce<<<1, Bc, 0, stream>>>(partial, (float*)d_out);
}

// Round 9
// 164.009 us; speedup vs baseline: 1.5683x; 1.5683x over previous
//
#include <hip/hip_runtime.h>

static constexpr int Lc = 512;
static constexpr int Bc = 256;
static constexpr int Tc = 128;

// DPP quad-permute add: combine the 4 h-slices (lanes of one quad), VALU-speed.
template <int CTRL>
__device__ __forceinline__ float quad_add(float x) {
  const int y = __builtin_amdgcn_update_dpp(0, __float_as_int(x), CTRL, 0xf, 0xf, true);
  return x + __int_as_float(y);
}

// One block per batch element (256 blocks = 1/CU). 512 threads = 8 waves.
// Thread tid: output tag j = tid>>2, reduction slice h = tid&3 (32 i's each).
// E-slice = 32 f32/lane (the one shape the allocator keeps in VGPRs: R3=76).
// p-space recurrence, exact power-of-2 rescale from p'[j=0] representative.
// Loop barrier = s_waitcnt lgkmcnt(0) + raw s_barrier: global em prefetches
// stay IN FLIGHT across the barrier (R3's __syncthreads drained vmcnt(0) and
// ate ~an HBM latency per step). Prefetch depth 3 (~2000cyc) > HBM ~900cyc.
__launch_bounds__(512, 1)
__global__ void crf_llh_kernel(const float* __restrict__ emis,
                               const int* __restrict__ tags,
                               const int* __restrict__ mask,
                               const float* __restrict__ startT,
                               const float* __restrict__ endT,
                               const float* __restrict__ trans,
                               float* __restrict__ partial)
{
  const int b    = blockIdx.x;
  const int tid  = threadIdx.x;
  const int j    = tid >> 2;   // 0..127
  const int h    = tid & 3;    // 0..3
  const int wid  = tid >> 6;   // 0..7
  const int lane = tid & 63;

  __shared__ __align__(16) float p_lds[2][4 * 36];   // padded segments
  __shared__ int expo_lds[2];                        // per-step scale exponent
  __shared__ float wredA[8];
  __shared__ float wredB[8];

  // ---------------- phase 0: numerator (gold-path score) ----------------
  float score = 0.0f;  // tid 0 only
  {
    const int t     = tid;
    const float mf  = (float)mask[t * Bc + b];
    const int tag_t = tags[t * Bc + b];
    float v = emis[((size_t)t * Bc + b) * Tc + tag_t] * mf;
    if (t >= 1) {
      const int tag_p = tags[(t - 1) * Bc + b];
      v += trans[tag_p * Tc + tag_t] * mf;
    }
    float c = mf;
    #pragma unroll
    for (int o = 1; o < 64; o <<= 1) {
      v += __shfl_xor(v, o);
      c += __shfl_xor(c, o);
    }
    if (lane == 0) { wredA[wid] = v; wredB[wid] = c; }
    __syncthreads();
    if (tid == 0) {
      float sv = 0.f, sc = 0.f;
      #pragma unroll
      for (int w = 0; w < 8; ++w) { sv += wredA[w]; sc += wredB[w]; }
      const int last_idx = (int)(sc + 0.5f) - 1;
      score = sv + startT[tags[b]] + endT[tags[last_idx * Bc + b]];
    }
    __syncthreads();
  }

  // ---------------- E-slice: 32 f32 VGPRs ----------------
  float Ecol[32];
  #pragma unroll
  for (int q = 0; q < 32; ++q)
    Ecol[q] = __expf(trans[(h * 32 + q) * Tc + j]);
  const float eEnd = __expf(endT[j]);

  // ---------------- init t = 0 ----------------
  const size_t strideT = (size_t)Bc * Tc;
  const float* emp = emis + (size_t)b * Tc + j;   // &em[0,b,j]
  const float lp0 = startT[j] + emp[0];

  float wm = lp0;
  #pragma unroll
  for (int o = 4; o < 64; o <<= 1) wm = fmaxf(wm, __shfl_xor(wm, o));
  if (lane == 0) wredA[wid] = wm;
  __syncthreads();
  float M0;
  {
    const float4* w4 = (const float4*)wredA;
    const float4 xa = w4[0], xb = w4[1];
    M0 = fmaxf(fmaxf(fmaxf(xa.x, xa.y), fmaxf(xa.z, xa.w)),
               fmaxf(fmaxf(xb.x, xb.y), fmaxf(xb.z, xb.w)));
  }
  float pj = __expf(lp0 - M0);                    // block max = 1 exactly
  if (h == 0)   p_lds[0][(j >> 5) * 36 + (j & 31)] = pj;
  if (tid == 0) expo_lds[0] = 0;

  // ---------------- em/mask prefetch pipeline, 3 deep ----------------
  float emR0 = emp[1 * strideT];     // em[t=1]
  float emR1 = emp[2 * strideT];
  float emR2 = emp[3 * strideT];
  int   mR0  = mask[1 * Bc + b];
  int   mR1  = mask[2 * Bc + b];
  int   mR2  = mask[3 * Bc + b];
  const float* emp3 = emp + 4 * strideT;   // next load addr (t=4)
  const int*   mp3  = mask + 4 * Bc + b;

  __syncthreads();   // p_lds[0], expo_lds[0] ready

  // ---------------- forward recurrence ----------------
  int Ksum = 0;
  int buf  = 0;
  #pragma unroll 2
  for (int t = 1; t < Lc; ++t) {
    // block-uniform rescale exponent (from p'[j=0] of previous step)
    const int e0 = expo_lds[buf];

    // GEMV slice: s = sum_{i in h-slice} p[i] * E[i][j]
    const float4* pv = (const float4*)&p_lds[buf][h * 36];
    float s0 = 0.f, s1 = 0.f, s2 = 0.f, s3 = 0.f;
    #pragma unroll
    for (int q = 0; q < 8; ++q) {
      const float4 pp = pv[q];
      s0 = fmaf(pp.x, Ecol[4 * q + 0], s0);
      s1 = fmaf(pp.y, Ecol[4 * q + 1], s1);
      s2 = fmaf(pp.z, Ecol[4 * q + 2], s2);
      s3 = fmaf(pp.w, Ecol[4 * q + 3], s3);
    }
    float s = (s0 + s1) + (s2 + s3);
    s = quad_add<0xB1>(s);   // + lane^1
    s = quad_add<0x4E>(s);   // + lane^2  -> full h sum

    const float eEm = __expf(emR0);

    // prefetch t+3: stays in flight across the raw barrier (no vmcnt drain)
    float emNew = 0.f; int mNew = 0;
    if (t + 3 < Lc) {
      emNew = emp3[0];
      mNew  = mp3[0];
      emp3 += strideT;
      mp3  += Bc;
    }

    const float r  = __uint_as_float((unsigned)(127 - e0) << 23);  // 2^-e0
    const float pn = (mR0 ? s * eEm : pj) * r;
    Ksum += e0;
    pj = pn;
    if (h == 0) p_lds[buf ^ 1][(j >> 5) * 36 + (j & 31)] = pn;
    if (tid == 0) {
      int e = (int)((__float_as_uint(pn) >> 23) & 0xff) - 127;
      expo_lds[buf ^ 1] = min(max(e, -100), 100);
    }

    // shift prefetch pipeline
    emR0 = emR1; emR1 = emR2; emR2 = emNew;
    mR0  = mR1;  mR1  = mR2;  mR2  = mNew;

    // raw barrier: drain LDS only; global loads remain outstanding
    asm volatile("s_waitcnt lgkmcnt(0)" ::: "memory");
    __builtin_amdgcn_s_barrier();
    asm volatile("" ::: "memory");

    buf ^= 1;
  }

  // ---------------- final: denom = M0 + Ksum*ln2 + log(sum p * e^end) ----
  float contrib = (h == 0) ? pj * eEnd : 0.f;
  #pragma unroll
  for (int o = 1; o < 64; o <<= 1) contrib += __shfl_xor(contrib, o);
  if (lane == 0) wredA[wid] = contrib;
  __syncthreads();
  if (tid == 0) {
    float ssum = 0.f;
    #pragma unroll
    for (int w = 0; w < 8; ++w) ssum += wredA[w];
    const float denom = M0 + (float)Ksum * 0.69314718055994531f + __logf(ssum);
    partial[b] = score - denom;
  }
}

// Deterministic final reduction of 256 per-batch llh values -> scalar.
__global__ void crf_reduce(const float* __restrict__ partial, float* __restrict__ out)
{
  const int tid = threadIdx.x;  // 256 threads
  float v = partial[tid];
  #pragma unroll
  for (int o = 1; o < 64; o <<= 1) v += __shfl_xor(v, o);
  __shared__ float ws[4];
  if ((tid & 63) == 0) ws[tid >> 6] = v;
  __syncthreads();
  if (tid == 0) out[0] = (ws[0] + ws[1]) + (ws[2] + ws[3]);
}

extern "C" void kernel_launch(void* const* d_in, const int* in_sizes, int n_in,
                              void* d_out, int out_size, void* d_ws, size_t ws_size,
                              hipStream_t stream)
{
  const float* emis   = (const float*)d_in[0];
  const int*   tags   = (const int*)d_in[1];
  const int*   mask   = (const int*)d_in[2];
  const float* startT = (const float*)d_in[3];
  const float* endT   = (const float*)d_in[4];
  const float* trans  = (const float*)d_in[5];

  float* partial = (float*)d_ws;  // 256 floats

  crf_llh_kernel<<<Bc, 512, 0, stream>>>(emis, tags, mask, startT, endT, trans, partial);
  crf_reduce<<<1, Bc, 0, stream>>>(partial, (float*)d_out);
}